// Round 1
// baseline (103.171 us; speedup 1.0000x reference)
//
#include <hip/hip_runtime.h>

#define BB 32
#define SS 2048
#define HH 768
#define LL 9
#define NROWS (BB * SS)
#define NCHUNK 64
#define TCHUNK (SS / NCHUNK)  // 32

// ---------------------------------------------------------------------------
// lse over 9 values (stable)
__device__ __forceinline__ float lse9(const float* v) {
  float m = v[0];
#pragma unroll
  for (int k = 1; k < 9; ++k) m = fmaxf(m, v[k]);
  float s = 0.f;
#pragma unroll
  for (int k = 0; k < 9; ++k) s += __expf(v[k] - m);
  return m + __logf(s);
}

// ---------------------------------------------------------------------------
// Kernel 1: emissions = hs @ W^T + b     (HBM-bound, wave-per-row)
// Lane owns k in {4*lane..4*lane+3} + {256..} + {512..}: every float4 load
// instruction is 64 lanes x 16B contiguous = 1024B coalesced.
__global__ __launch_bounds__(256, 2)
void emis_gemm(const float* __restrict__ hs, const float* __restrict__ W,
               const float* __restrict__ bias, float* __restrict__ em) {
  const int lane = threadIdx.x & 63;
  const int wave = blockIdx.x * (blockDim.x >> 6) + (threadIdx.x >> 6);
  const int nw = gridDim.x * (blockDim.x >> 6);

  // preload this lane's W slice: 9 outputs x 12 k-values = 108 VGPRs
  float wreg[LL][12];
#pragma unroll
  for (int l = 0; l < LL; ++l) {
#pragma unroll
    for (int p = 0; p < 3; ++p) {
      float4 t = *reinterpret_cast<const float4*>(W + l * HH + p * 256 + lane * 4);
      wreg[l][p * 4 + 0] = t.x;
      wreg[l][p * 4 + 1] = t.y;
      wreg[l][p * 4 + 2] = t.z;
      wreg[l][p * 4 + 3] = t.w;
    }
  }

  for (int row = wave; row < NROWS; row += nw) {
    const float4* hr = reinterpret_cast<const float4*>(hs + (size_t)row * HH);
    float4 h0 = hr[lane];
    float4 h1 = hr[64 + lane];
    float4 h2 = hr[128 + lane];
    float hh[12] = {h0.x, h0.y, h0.z, h0.w, h1.x, h1.y,
                    h1.z, h1.w, h2.x, h2.y, h2.z, h2.w};
    float acc[LL];
#pragma unroll
    for (int l = 0; l < LL; ++l) {
      float s = 0.f;
#pragma unroll
      for (int q = 0; q < 12; ++q) s = fmaf(hh[q], wreg[l][q], s);
      acc[l] = s;
    }
    // butterfly reduce across the 64-lane wave
#pragma unroll
    for (int off = 32; off; off >>= 1) {
#pragma unroll
      for (int l = 0; l < LL; ++l) acc[l] += __shfl_xor(acc[l], off, 64);
    }
    if (lane == 0) {
      float* o = em + (size_t)row * LL;
#pragma unroll
      for (int l = 0; l < LL; ++l) o[l] = acc[l] + bias[l];
    }
  }
}

// ---------------------------------------------------------------------------
// Kernel 2: gold-path score (numerator), one block per batch
__global__ __launch_bounds__(256)
void crf_num(const float* __restrict__ em, const int* __restrict__ lab,
             const float* __restrict__ startT, const float* __restrict__ endT,
             const float* __restrict__ trans, float* __restrict__ num) {
  const int b = blockIdx.x, tid = threadIdx.x;
  const int* lb = lab + b * SS;
  const float* eb = em + (size_t)b * SS * LL;
  float sc = 0.f;
  int cnt = 0;
  for (int t = tid; t < SS; t += blockDim.x) {
    int lv = lb[t];
    int m = (lv != -100);
    int tg = m ? lv : 0;
    cnt += m;
    if (t == 0) {
      sc += startT[tg] + eb[tg];
    } else if (m) {
      int pv = lb[t - 1];
      int tp = (pv != -100) ? pv : 0;
      sc += trans[tp * LL + tg] + eb[(size_t)t * LL + tg];
    }
  }
  __shared__ float sred[256];
  __shared__ int cred[256];
  sred[tid] = sc;
  cred[tid] = cnt;
  __syncthreads();
  for (int s = blockDim.x / 2; s; s >>= 1) {
    if (tid < s) {
      sred[tid] += sred[tid + s];
      cred[tid] += cred[tid + s];
    }
    __syncthreads();
  }
  if (tid == 0) {
    int se = cred[0] - 1;  // seq_end
    int lt = lb[se];
    if (lt == -100) lt = 0;
    num[b] = sred[0] + endT[lt];
  }
}

// ---------------------------------------------------------------------------
// Kernel 3: per-chunk log-semiring transfer matrices.
// Block = 128 threads (81 active: thread = (i,j)), grid = B * NCHUNK.
// P <- P (x) M_t, M_t[k][j] = trans[k][j] + em[t][j], skipped when masked.
__global__ __launch_bounds__(128)
void crf_chunk(const float* __restrict__ em, const int* __restrict__ lab,
               const float* __restrict__ trans, float* __restrict__ Pout) {
  const int blk = blockIdx.x;
  const int b = blk / NCHUNK, c = blk % NCHUNK;
  const int tid = threadIdx.x;
  const bool act = tid < 81;
  const int i = tid / 9, j = tid % 9;
  __shared__ float P[81];
  float tc[9];
  if (act) {
#pragma unroll
    for (int k = 0; k < 9; ++k) tc[k] = trans[k * 9 + j];
    P[tid] = (i == j) ? 0.f : -1e30f;  // log-semiring identity
  }
  __syncthreads();
  const float* eb = em + (size_t)b * SS * LL;
  const int* lb = lab + b * SS;
  int t0 = c * TCHUNK;
  if (t0 == 0) t0 = 1;  // step 0 is alpha0, not a matrix
  const int t1 = (c + 1) * TCHUNK;
  for (int t = t0; t < t1; ++t) {
    if (lb[t] != -100) {  // uniform across block
      float r = 0.f;
      if (act) {
        float v[9];
#pragma unroll
        for (int k = 0; k < 9; ++k) v[k] = P[i * 9 + k] + tc[k];
        r = lse9(v) + eb[(size_t)t * LL + j];
      }
      __syncthreads();
      if (act) P[tid] = r;
      __syncthreads();
    }
  }
  if (act) Pout[(size_t)blk * 81 + tid] = P[tid];
}

// ---------------------------------------------------------------------------
// Kernel 4: fold alpha0 through the 64 chunk matrices, one block per batch.
__global__ __launch_bounds__(64)
void crf_fold(const float* __restrict__ Pm, const float* __restrict__ em,
              const float* __restrict__ startT, const float* __restrict__ endT,
              float* __restrict__ den) {
  const int b = blockIdx.x, j = threadIdx.x;
  __shared__ float alpha[9];
  if (j < 9) alpha[j] = startT[j] + em[(size_t)b * SS * LL + j];
  __syncthreads();
  const float* Pb = Pm + (size_t)b * NCHUNK * 81;
  float pv[9];
  if (j < 9) {
#pragma unroll
    for (int k = 0; k < 9; ++k) pv[k] = Pb[k * 9 + j];
  }
  for (int c = 0; c < NCHUNK; ++c) {
    float r = 0.f;
    if (j < 9) {
      float cv[9];
#pragma unroll
      for (int k = 0; k < 9; ++k) cv[k] = pv[k];
      if (c + 1 < NCHUNK) {  // prefetch next chunk's column
#pragma unroll
        for (int k = 0; k < 9; ++k) pv[k] = Pb[(size_t)(c + 1) * 81 + k * 9 + j];
      }
      float v[9];
#pragma unroll
      for (int k = 0; k < 9; ++k) v[k] = alpha[k] + cv[k];
      r = lse9(v);
    }
    __syncthreads();
    if (j < 9) alpha[j] = r;
    __syncthreads();
  }
  if (j == 0) {
    float v[9];
#pragma unroll
    for (int k = 0; k < 9; ++k) v[k] = alpha[k] + endT[k];
    den[b] = lse9(v);
  }
}

// ---------------------------------------------------------------------------
// Kernel 5: loss = -mean(num - den)
__global__ __launch_bounds__(64)
void finalize(const float* __restrict__ num, const float* __restrict__ den,
              float* __restrict__ out) {
  int l = threadIdx.x;
  float v = (l < BB) ? (num[l] - den[l]) : 0.f;
#pragma unroll
  for (int off = 32; off; off >>= 1) v += __shfl_xor(v, off, 64);
  if (l == 0) out[0] = -v / (float)BB;
}

// ---------------------------------------------------------------------------
extern "C" void kernel_launch(void* const* d_in, const int* in_sizes, int n_in,
                              void* d_out, int out_size, void* d_ws, size_t ws_size,
                              hipStream_t stream) {
  const float* hs = (const float*)d_in[0];      // [B,S,H]
  const float* W = (const float*)d_in[1];       // [L,H]
  const float* bias = (const float*)d_in[2];    // [L]
  const float* startT = (const float*)d_in[3];  // [L]
  const float* endT = (const float*)d_in[4];    // [L]
  const float* trans = (const float*)d_in[5];   // [L,L]
  const int* labels = (const int*)d_in[6];      // [B,S]
  // d_in[7] = attention_mask (unused by the reference)

  float* out = (float*)d_out;    // out[0] = loss, out[1..] = emissions [B,S,L]
  float* em = out + 1;

  float* wsf = (float*)d_ws;
  float* num = wsf;          // [32]
  float* den = wsf + 32;     // [32]
  float* Pm = wsf + 64;      // [B*NCHUNK*81]

  emis_gemm<<<1024, 256, 0, stream>>>(hs, W, bias, em);
  crf_num<<<BB, 256, 0, stream>>>(em, labels, startT, endT, trans, num);
  crf_chunk<<<BB * NCHUNK, 128, 0, stream>>>(em, labels, trans, Pm);
  crf_fold<<<BB, 64, 0, stream>>>(Pm, em, startT, endT, den);
  finalize<<<1, 64, 0, stream>>>(num, den, out);
}